// Round 14
// baseline (24.553 us; speedup 1.0000x reference)
//
#include <hip/hip_runtime.h>
#include <math.h>

#define NGAUSS 2000
#define IMW 128
#define IMH 128
#define NPIX (IMW*IMH)
#define NW 16                     // waves per block (both kernels)
#define SEGSZ ((NGAUSS + NW - 1) / NW)   // 125 gaussians per wave-segment
#define PREPBLK (NGAUSS / NW)            // 125 preprank blocks

// ---------------- fused prep + stable rank sort + scatter ----------------
// 125 blocks x 16 waves; wave w of block b owns gaussian i = b*16+w.
// Block stages all 2000 depths in LDS (coalesced); rank via ballot/popc.
// Outputs:
//   soaCull[k*2000 + rank], k = 0:m2x 1:m2y 2:s_cull   (per-lane cull reads)
//   aos[rank*3 + 0..2] (float4):                        (wave-uniform s_loads)
//     q0 = { m2x, m2y, q0s, q1s }
//     q1 = { q2s, c0,  cr,  cg  }
//     q2 = { cb,  depth, 0, 0 }
// (qXs pre-scaled by -log2(e) for exp2; s_cull = lambda_min(Q)*log2(e))
__global__ __launch_bounds__(1024) void preprank_kernel(
    const float* __restrict__ means3D, const float* __restrict__ covs3d,
    const float* __restrict__ colors, const float* __restrict__ opac,
    const float* __restrict__ Km, const float* __restrict__ Rm,
    const float* __restrict__ tv,
    float* __restrict__ soaCull, float4* __restrict__ aos)
{
    __shared__ float sdep[2048];

    int tid  = threadIdx.x;
    int lane = tid & 63;
    int w    = tid >> 6;
    int i    = blockIdx.x * NW + w;        // this wave's gaussian

    float R0 = Rm[0], R1 = Rm[1], R2 = Rm[2];
    float R3 = Rm[3], R4 = Rm[4], R5 = Rm[5];
    float R6 = Rm[6], R7 = Rm[7], R8 = Rm[8];
    float t0 = tv[0], t1v = tv[1], t2 = tv[2];

    // ---- stage all depths in LDS (coalesced) ----
    for (int g = tid; g < 2048; g += 1024) {
        float dep = 3.0e38f;                // pad > all real depths
        if (g < NGAUSS) {
            float jx = means3D[3*g+0], jy = means3D[3*g+1], jz = means3D[3*g+2];
            dep = fmaxf(R6*jx + R7*jy + R8*jz + t2, 1.0f);
        }
        sdep[g] = dep;
    }
    __syncthreads();

    // ---- rank via LDS + ballot/popc (wave-uniform result) ----
    float di = sdep[i];
    int rank = 0;
    for (int base = 0; base < 2048; base += 64) {
        int j = base + lane;
        float dj = sdep[j];
        bool lt = (j != i) && ((dj < di) || (dj == di && j < i));  // stable; pad never lt
        rank += (int)__popcll(__ballot(lt));
    }

    // ---- prep (redundant on all lanes of the wave) ----
    float mx = means3D[3*i+0], my = means3D[3*i+1], mz = means3D[3*i+2];
    float camx = R0*mx + R1*my + R2*mz + t0;
    float camy = R3*mx + R4*my + R5*mz + t1v;
    float camz = R6*mx + R7*my + R8*mz + t2;
    float depth = fmaxf(camz, 1.0f);
    bool valid = (depth > 1.0f) && (depth < 50.0f);

    float fx = Km[0], cx = Km[2], fy = Km[4], cy = Km[5];
    float invz = 1.0f / camz;
    float m2x = (fx*camx + cx*camz) * invz;
    float m2y = (fy*camy + cy*camz) * invz;
    float J00 = fx*invz, J02 = -fx*camx*invz*invz;
    float J11 = fy*invz, J12 = -fy*camy*invz*invz;

    float S0 = covs3d[9*i+0], S1 = covs3d[9*i+1], S2 = covs3d[9*i+2];
    float S3 = covs3d[9*i+3], S4 = covs3d[9*i+4], S5 = covs3d[9*i+5];
    float S6 = covs3d[9*i+6], S7 = covs3d[9*i+7], S8 = covs3d[9*i+8];

    float RS0 = R0*S0 + R1*S3 + R2*S6;
    float RS1 = R0*S1 + R1*S4 + R2*S7;
    float RS2 = R0*S2 + R1*S5 + R2*S8;
    float RS3 = R3*S0 + R4*S3 + R5*S6;
    float RS4 = R3*S1 + R4*S4 + R5*S7;
    float RS5 = R3*S2 + R4*S5 + R5*S8;
    float RS6 = R6*S0 + R7*S3 + R8*S6;
    float RS7 = R6*S1 + R7*S4 + R8*S7;
    float RS8 = R6*S2 + R7*S5 + R8*S8;

    float Sc0 = RS0*R0 + RS1*R1 + RS2*R2;
    float Sc1 = RS0*R3 + RS1*R4 + RS2*R5;
    float Sc2 = RS0*R6 + RS1*R7 + RS2*R8;
    float Sc3 = RS3*R0 + RS4*R1 + RS5*R2;
    float Sc4 = RS3*R3 + RS4*R4 + RS5*R5;
    float Sc5 = RS3*R6 + RS4*R7 + RS5*R8;
    float Sc6 = RS6*R0 + RS7*R1 + RS8*R2;
    float Sc7 = RS6*R3 + RS7*R4 + RS8*R5;
    float Sc8 = RS6*R6 + RS7*R7 + RS8*R8;

    float A00 = J00*Sc0 + J02*Sc6;
    float A01 = J00*Sc1 + J02*Sc7;
    float A02 = J00*Sc2 + J02*Sc8;
    float A10 = J11*Sc3 + J12*Sc6;
    float A11 = J11*Sc4 + J12*Sc7;
    float A12 = J11*Sc5 + J12*Sc8;

    float a = A00*J00 + A02*J02 + 1e-4f;
    float b = A01*J11 + A02*J12;
    float c = A10*J00 + A12*J02;
    float d = A11*J11 + A12*J12 + 1e-4f;

    float det = a*d - b*c;
    float invdet = 1.0f / det;
    float q0u = d*invdet;
    float q1u = -(b + c)*invdet;
    float q2u = a*invdet;
    // smallest eigenvalue of [[q0u, q1u/2],[q1u/2, q2u]] for conservative cull
    float mh = 0.5f*(q0u + q2u);
    float dh = 0.5f*(q0u - q2u);
    float oh = 0.5f*q1u;
    float lmin = mh - sqrtf(dh*dh + oh*oh);
    const float L2E = 1.4426950408889634f;
    float s_cull = lmin * L2E;
    float q0 = -q0u * L2E;
    float q1 = -q1u * L2E;
    float q2 = -q2u * L2E;
    float c0 = opac[i] * 0.15915494309189535f / sqrtf(det);
    if (!valid) { m2x = 0.f; m2y = 0.f; q0 = 0.f; q1 = 0.f; q2 = 0.f; c0 = 0.f; s_cull = 3.0e38f; }

    float cr = colors[3*i+0], cg = colors[3*i+1], cb = colors[3*i+2];
    if (lane < 3) {
        float4 v = (lane == 0) ? make_float4(m2x, m2y, q0, q1)
                 : (lane == 1) ? make_float4(q2, c0, cr, cg)
                               : make_float4(cb, depth, 0.f, 0.f);
        aos[(size_t)rank*3 + lane] = v;
        float sv = (lane == 0) ? m2x : (lane == 1) ? m2y : s_cull;
        soaCull[lane*NGAUSS + rank] = sv;
    }
}

// ---------------- render: s_load survivor walk, 2-deep pipelined ----------------
// Block = 64x1 px tile, 16 waves split depth into 125-gaussian segments.
// Cull: per-lane SoA reads (coalesced) -> ballot. Walk: survivor index is
// wave-uniform -> AoS loads compile to s_load_dwordx4 (scalar pipe, no
// VALU/LDS issue); next survivor's 3 quads prefetched during current eval.
// Reference semantics: weight[0]=a_0; weight[n>=1]=a_n*(1-a_n)*prod_{k<n}(1-a_k)
__global__ __launch_bounds__(1024) void render_fused(
    const float* __restrict__ soaCull, const float4* __restrict__ aos,
    float* __restrict__ out)
{
    __shared__ float4 pOut[NW*64];

    int tid  = threadIdx.x;
    int lane = tid & 63;
    int w    = tid >> 6;
    int bid  = blockIdx.x;
    int row  = bid >> 1;
    int xoff = (bid & 1) * 64;

    float px = (float)(xoff + lane);
    float py = (float)row;
    float x0 = (float)xoff, x1 = x0 + 63.0f;

    float Cr = 0.f, Cg = 0.f, Cb = 0.f, T = 1.f;

    int segBase = w * SEGSZ;

    // ---- per-lane cull params: chunk A (lanes=first 64), chunk B (rest) ----
    int gA = segBase + lane;
    bool vB = (64 + lane) < SEGSZ;
    int gB = vB ? (segBase + 64 + lane) : segBase;
    float Amx = soaCull[0*NGAUSS+gA], Amy = soaCull[1*NGAUSS+gA], Asc = soaCull[2*NGAUSS+gA];
    float Bmx = soaCull[0*NGAUSS+gB], Bmy = soaCull[1*NGAUSS+gB], Bsc = soaCull[2*NGAUSS+gB];

    #pragma unroll
    for (int chunk = 0; chunk < 2; ++chunk) {
        int cbase = segBase + chunk*64;
        float cmx = chunk ? Bmx : Amx;
        float cmy = chunk ? Bmy : Amy;
        float csc = chunk ? Bsc : Asc;
        bool inb = chunk ? vB : true;
        float dxm = fmaxf(0.f, fmaxf(x0 - cmx, cmx - x1));
        float dym = fabsf(py - cmy);
        bool keep = inb && (csc * fmaf(dxm, dxm, dym*dym) <= 24.f);  // alpha >= c0*2^-24
        unsigned long long mask = __ballot(keep);
        if (!mask) continue;

        int b0 = __builtin_ctzll(mask);
        int gn = cbase + b0;
        float4 P0 = aos[(size_t)gn*3+0];    // uniform addr -> s_load_dwordx4
        float4 P1 = aos[(size_t)gn*3+1];
        float4 P2 = aos[(size_t)gn*3+2];
        (void)P2;

        while (true) {
            unsigned long long m2 = mask & (mask - 1);
            int b2 = m2 ? __builtin_ctzll(m2) : 0;
            int gn2 = cbase + b2;
            // prefetch next survivor's quads (s_load, hidden under eval)
            float4 N0 = aos[(size_t)gn2*3+0];
            float4 N1 = aos[(size_t)gn2*3+1];
            float4 N2 = aos[(size_t)gn2*3+2];
            (void)N2;
            // eval current survivor
            float dy = py - P0.y;
            float dx = px - P0.x;
            float e  = fmaf(fmaf(P0.z, dx, P0.w*dy), dx, (P1.x*dy)*dy);
            float al = P1.y * exp2f(e);              // alpha
            float wgt = T * al;                      // T*alpha
            float sel = (gn == 0) ? 0.f : al;        // rank-0: weight = alpha exactly
            float f = fmaf(-sel, wgt, wgt);          // T*alpha*(1-alpha)
            Cr = fmaf(f, P1.z, Cr);
            Cg = fmaf(f, P1.w, Cg);
            Cb = fmaf(f, P2.x, Cb);
            T -= wgt;                                // T *= (1-alpha)
            mask = m2;
            if (!mask) break;
            gn = gn2; P0 = N0; P1 = N1; P2 = N2;
        }
    }

    pOut[w*64 + lane] = make_float4(Cr, Cg, Cb, T);
    __syncthreads();

    // ---- wave 0 composites the 16 depth-ordered partials for its 64 px ----
    if (tid < 64) {
        float cR = 0.f, cG = 0.f, cB = 0.f, tA = 1.f;
        #pragma unroll
        for (int s = 0; s < NW; ++s) {
            float4 v = pOut[s*64 + tid];
            cR = fmaf(tA, v.x, cR);
            cG = fmaf(tA, v.y, cG);
            cB = fmaf(tA, v.z, cB);
            tA *= v.w;
        }
        int p = row*IMW + xoff + tid;
        out[3*p+0] = cR; out[3*p+1] = cG; out[3*p+2] = cB;
    }
}

extern "C" void kernel_launch(void* const* d_in, const int* in_sizes, int n_in,
                              void* d_out, int out_size, void* d_ws, size_t ws_size,
                              hipStream_t stream)
{
    const float* means3D = (const float*)d_in[0];
    const float* covs3d  = (const float*)d_in[1];
    const float* colors  = (const float*)d_in[2];
    const float* opac    = (const float*)d_in[3];
    const float* Km      = (const float*)d_in[4];
    const float* Rm      = (const float*)d_in[5];
    const float* tv      = (const float*)d_in[6];

    float*  soaCull = (float*)d_ws;                 // 3 x NGAUSS floats = 24 KB
    float4* aos     = (float4*)((float*)d_ws + 6144); // 16B-aligned; NGAUSS*3 float4 = 96 KB

    preprank_kernel<<<PREPBLK, 1024, 0, stream>>>(
        means3D, covs3d, colors, opac, Km, Rm, tv, soaCull, aos);
    render_fused<<<NPIX/64, 1024, 0, stream>>>(soaCull, aos, (float*)d_out);
}

// Round 15
// 23.796 us; speedup vs baseline: 1.0318x; 1.0318x over previous
//
#include <hip/hip_runtime.h>
#include <math.h>

#define NGAUSS 2000
#define IMW 128
#define IMH 128
#define NPIX (IMW*IMH)
#define NW 16                     // waves per block (both kernels)
#define SEGSZ ((NGAUSS + NW - 1) / NW)   // 125 gaussians per wave-segment
#define PREPBLK (NGAUSS / NW)            // 125 preprank blocks

__device__ inline float rdlane(float x, int l) {
    return __uint_as_float(__builtin_amdgcn_readlane(__float_as_uint(x), l));
}

// ---------------- fused prep + stable rank sort + SoA scatter ----------------
// 125 blocks x 16 waves; wave w of block b owns gaussian i = b*16+w.
// Block stages all 2000 depths in LDS (coalesced), ranks come from LDS reads.
// SoA output: soa[k*2000 + rank], k =
//   0:m2x 1:m2y 2:s_cull 3:q0s 4:q1s 5:q2s 6:c0 7:cr 8:cg 9:cb
// (qXs pre-scaled by -log2(e) for exp2; s_cull = lambda_min(Q)*log2(e))
__global__ __launch_bounds__(1024) void preprank_kernel(
    const float* __restrict__ means3D, const float* __restrict__ covs3d,
    const float* __restrict__ colors, const float* __restrict__ opac,
    const float* __restrict__ Km, const float* __restrict__ Rm,
    const float* __restrict__ tv, float* __restrict__ soa)
{
    __shared__ float sdep[2048];

    int tid  = threadIdx.x;
    int lane = tid & 63;
    int w    = tid >> 6;
    int i    = blockIdx.x * NW + w;        // this wave's gaussian

    float R0 = Rm[0], R1 = Rm[1], R2 = Rm[2];
    float R3 = Rm[3], R4 = Rm[4], R5 = Rm[5];
    float R6 = Rm[6], R7 = Rm[7], R8 = Rm[8];
    float t0 = tv[0], t1v = tv[1], t2 = tv[2];

    // ---- stage all depths in LDS (coalesced) ----
    for (int g = tid; g < 2048; g += 1024) {
        float dep = 3.0e38f;                // pad > all real depths
        if (g < NGAUSS) {
            float jx = means3D[3*g+0], jy = means3D[3*g+1], jz = means3D[3*g+2];
            dep = fmaxf(R6*jx + R7*jy + R8*jz + t2, 1.0f);
        }
        sdep[g] = dep;
    }
    __syncthreads();

    // ---- rank via LDS + ballot/popc (wave-uniform result) ----
    float di = sdep[i];
    int rank = 0;
    for (int base = 0; base < 2048; base += 64) {
        int j = base + lane;
        float dj = sdep[j];
        bool lt = (j != i) && ((dj < di) || (dj == di && j < i));  // stable; pad never lt
        rank += (int)__popcll(__ballot(lt));
    }

    // ---- prep (redundant on all lanes of the wave) ----
    float mx = means3D[3*i+0], my = means3D[3*i+1], mz = means3D[3*i+2];
    float camx = R0*mx + R1*my + R2*mz + t0;
    float camy = R3*mx + R4*my + R5*mz + t1v;
    float camz = R6*mx + R7*my + R8*mz + t2;
    float depth = fmaxf(camz, 1.0f);
    bool valid = (depth > 1.0f) && (depth < 50.0f);

    float fx = Km[0], cx = Km[2], fy = Km[4], cy = Km[5];
    float invz = 1.0f / camz;
    float m2x = (fx*camx + cx*camz) * invz;
    float m2y = (fy*camy + cy*camz) * invz;
    float J00 = fx*invz, J02 = -fx*camx*invz*invz;
    float J11 = fy*invz, J12 = -fy*camy*invz*invz;

    float S0 = covs3d[9*i+0], S1 = covs3d[9*i+1], S2 = covs3d[9*i+2];
    float S3 = covs3d[9*i+3], S4 = covs3d[9*i+4], S5 = covs3d[9*i+5];
    float S6 = covs3d[9*i+6], S7 = covs3d[9*i+7], S8 = covs3d[9*i+8];

    float RS0 = R0*S0 + R1*S3 + R2*S6;
    float RS1 = R0*S1 + R1*S4 + R2*S7;
    float RS2 = R0*S2 + R1*S5 + R2*S8;
    float RS3 = R3*S0 + R4*S3 + R5*S6;
    float RS4 = R3*S1 + R4*S4 + R5*S7;
    float RS5 = R3*S2 + R4*S5 + R5*S8;
    float RS6 = R6*S0 + R7*S3 + R8*S6;
    float RS7 = R6*S1 + R7*S4 + R8*S7;
    float RS8 = R6*S2 + R7*S5 + R8*S8;

    float Sc0 = RS0*R0 + RS1*R1 + RS2*R2;
    float Sc1 = RS0*R3 + RS1*R4 + RS2*R5;
    float Sc2 = RS0*R6 + RS1*R7 + RS2*R8;
    float Sc3 = RS3*R0 + RS4*R1 + RS5*R2;
    float Sc4 = RS3*R3 + RS4*R4 + RS5*R5;
    float Sc5 = RS3*R6 + RS4*R7 + RS5*R8;
    float Sc6 = RS6*R0 + RS7*R1 + RS8*R2;
    float Sc7 = RS6*R3 + RS7*R4 + RS8*R5;
    float Sc8 = RS6*R6 + RS7*R7 + RS8*R8;

    float A00 = J00*Sc0 + J02*Sc6;
    float A01 = J00*Sc1 + J02*Sc7;
    float A02 = J00*Sc2 + J02*Sc8;
    float A10 = J11*Sc3 + J12*Sc6;
    float A11 = J11*Sc4 + J12*Sc7;
    float A12 = J11*Sc5 + J12*Sc8;

    float a = A00*J00 + A02*J02 + 1e-4f;
    float b = A01*J11 + A02*J12;
    float c = A10*J00 + A12*J02;
    float d = A11*J11 + A12*J12 + 1e-4f;

    float det = a*d - b*c;
    float invdet = 1.0f / det;
    float q0u = d*invdet;
    float q1u = -(b + c)*invdet;
    float q2u = a*invdet;
    // smallest eigenvalue of [[q0u, q1u/2],[q1u/2, q2u]] for conservative cull
    float mh = 0.5f*(q0u + q2u);
    float dh = 0.5f*(q0u - q2u);
    float oh = 0.5f*q1u;
    float lmin = mh - sqrtf(dh*dh + oh*oh);
    const float L2E = 1.4426950408889634f;
    float s_cull = lmin * L2E;
    float q0 = -q0u * L2E;
    float q1 = -q1u * L2E;
    float q2 = -q2u * L2E;
    float c0 = opac[i] * 0.15915494309189535f / sqrtf(det);
    if (!valid) { m2x = 0.f; m2y = 0.f; q0 = 0.f; q1 = 0.f; q2 = 0.f; c0 = 0.f; s_cull = 3.0e38f; }

    float cr = colors[3*i+0], cg = colors[3*i+1], cb = colors[3*i+2];
    float v = (lane == 0) ? m2x
            : (lane == 1) ? m2y
            : (lane == 2) ? s_cull
            : (lane == 3) ? q0
            : (lane == 4) ? q1
            : (lane == 5) ? q2
            : (lane == 6) ? c0
            : (lane == 7) ? cr
            : (lane == 8) ? cg
                          : cb;
    if (lane < 10) soa[lane*NGAUSS + rank] = v;
}

// ---------------- render: reg-resident segment, no LDS staging ----------------
// Block = 64x1 px tile, 16 waves split depth into 125-gaussian segments.
// Each lane HOLDS the params of its segment's gaussians (2 chunks x 10 regs,
// stride-1 coalesced SoA loads). Cull on own regs -> ballot -> survivors
// broadcast via v_readlane from holder lane. 16 partials combined in 16KB LDS.
// Reference semantics: weight[0]=a_0; weight[n>=1]=a_n*(1-a_n)*prod_{k<n}(1-a_k)
__global__ __launch_bounds__(1024) void render_fused(
    const float* __restrict__ soa, float* __restrict__ out)
{
    __shared__ float4 pOut[NW*64];

    int tid  = threadIdx.x;
    int lane = tid & 63;
    int w    = tid >> 6;
    int bid  = blockIdx.x;
    int row  = bid >> 1;
    int xoff = (bid & 1) * 64;

    float px = (float)(xoff + lane);
    float py = (float)row;
    float x0 = (float)xoff, x1 = x0 + 63.0f;

    float Cr = 0.f, Cg = 0.f, Cb = 0.f, T = 1.f;

    int segBase = w * SEGSZ;

    // ---- load own-lane params: chunk A (lane 0..63), chunk B (lane 64..124) ----
    int gA = segBase + lane;
    bool vB = (64 + lane) < SEGSZ;
    int gB = vB ? (segBase + 64 + lane) : segBase;
    float A0 = soa[0*NGAUSS+gA], A1 = soa[1*NGAUSS+gA], A2 = soa[2*NGAUSS+gA];
    float A3 = soa[3*NGAUSS+gA], A4 = soa[4*NGAUSS+gA], A5 = soa[5*NGAUSS+gA];
    float A6 = soa[6*NGAUSS+gA], A7 = soa[7*NGAUSS+gA], A8 = soa[8*NGAUSS+gA];
    float A9 = soa[9*NGAUSS+gA];
    float B0 = soa[0*NGAUSS+gB], B1 = soa[1*NGAUSS+gB], B2 = soa[2*NGAUSS+gB];
    float B3 = soa[3*NGAUSS+gB], B4 = soa[4*NGAUSS+gB], B5 = soa[5*NGAUSS+gB];
    float B6 = soa[6*NGAUSS+gB], B7 = soa[7*NGAUSS+gB], B8 = soa[8*NGAUSS+gB];
    float B9 = soa[9*NGAUSS+gB];

    // ---- chunk A ----
    {
        float dxm = fmaxf(0.f, fmaxf(x0 - A0, A0 - x1));
        float dym = fabsf(py - A1);
        bool keep = A2 * fmaf(dxm, dxm, dym*dym) <= 24.f;   // alpha >= c0*2^-24
        unsigned long long mask = __ballot(keep);
        while (mask) {
            int b = __builtin_ctzll(mask);
            mask &= mask - 1;
            int gn = segBase + b;
            float gmx = rdlane(A0,b), gmy = rdlane(A1,b);
            float gq0 = rdlane(A3,b), gq1 = rdlane(A4,b), gq2 = rdlane(A5,b);
            float gc0 = rdlane(A6,b), gcr = rdlane(A7,b);
            float gcg = rdlane(A8,b), gcb = rdlane(A9,b);
            float dy = py - gmy;
            float dx = px - gmx;
            float e  = fmaf(fmaf(gq0, dx, gq1*dy), dx, (gq2*dy)*dy);
            float al = gc0 * exp2f(e);               // alpha
            float wgt = T * al;                      // T*alpha
            float sel = (gn == 0) ? 0.f : al;        // rank-0: weight = alpha exactly
            float f = fmaf(-sel, wgt, wgt);          // T*alpha*(1-alpha)
            Cr = fmaf(f, gcr, Cr);
            Cg = fmaf(f, gcg, Cg);
            Cb = fmaf(f, gcb, Cb);
            T -= wgt;                                // T *= (1-alpha)
        }
    }
    // ---- chunk B ----
    {
        float dxm = fmaxf(0.f, fmaxf(x0 - B0, B0 - x1));
        float dym = fabsf(py - B1);
        bool keep = vB && (B2 * fmaf(dxm, dxm, dym*dym) <= 24.f);
        unsigned long long mask = __ballot(keep);
        while (mask) {
            int b = __builtin_ctzll(mask);
            mask &= mask - 1;
            float gmx = rdlane(B0,b), gmy = rdlane(B1,b);
            float gq0 = rdlane(B3,b), gq1 = rdlane(B4,b), gq2 = rdlane(B5,b);
            float gc0 = rdlane(B6,b), gcr = rdlane(B7,b);
            float gcg = rdlane(B8,b), gcb = rdlane(B9,b);
            float dy = py - gmy;
            float dx = px - gmx;
            float e  = fmaf(fmaf(gq0, dx, gq1*dy), dx, (gq2*dy)*dy);
            float al = gc0 * exp2f(e);
            float wgt = T * al;
            float f = fmaf(-al, wgt, wgt);           // gn>0 always here
            Cr = fmaf(f, gcr, Cr);
            Cg = fmaf(f, gcg, Cg);
            Cb = fmaf(f, gcb, Cb);
            T -= wgt;
        }
    }

    pOut[w*64 + lane] = make_float4(Cr, Cg, Cb, T);
    __syncthreads();

    // ---- wave 0 composites the 16 depth-ordered partials for its 64 px ----
    if (tid < 64) {
        float cR = 0.f, cG = 0.f, cB = 0.f, tA = 1.f;
        #pragma unroll
        for (int s = 0; s < NW; ++s) {
            float4 v = pOut[s*64 + tid];
            cR = fmaf(tA, v.x, cR);
            cG = fmaf(tA, v.y, cG);
            cB = fmaf(tA, v.z, cB);
            tA *= v.w;
        }
        int p = row*IMW + xoff + tid;
        out[3*p+0] = cR; out[3*p+1] = cG; out[3*p+2] = cB;
    }
}

extern "C" void kernel_launch(void* const* d_in, const int* in_sizes, int n_in,
                              void* d_out, int out_size, void* d_ws, size_t ws_size,
                              hipStream_t stream)
{
    const float* means3D = (const float*)d_in[0];
    const float* covs3d  = (const float*)d_in[1];
    const float* colors  = (const float*)d_in[2];
    const float* opac    = (const float*)d_in[3];
    const float* Km      = (const float*)d_in[4];
    const float* Rm      = (const float*)d_in[5];
    const float* tv      = (const float*)d_in[6];

    float* soa = (float*)d_ws;   // 10 arrays x NGAUSS floats = 80 KB

    preprank_kernel<<<PREPBLK, 1024, 0, stream>>>(
        means3D, covs3d, colors, opac, Km, Rm, tv, soa);
    render_fused<<<NPIX/64, 1024, 0, stream>>>(soa, (float*)d_out);
}